// Round 12
// baseline (1823.211 us; speedup 1.0000x reference)
//
#include <hip/hip_runtime.h>
#include <stdint.h>

// LSTM (packed sequence) on MI355X — round 12.
// T=512, B=64, D=512, H=512. out[t,b,:] = masked h_t.
//
// R11 base (256 WGs = 8 groups x 32 jblk, GR=8, 2 WGs/CU, K-HALF SPLIT
// tagged LLC poll + 4-wave half barrier, parity h-tile, parity x-tile,
// early h-store, 1 full + 1 half barrier per step) + one change:
//   POLL PREFETCH: the tail of step t issues the first probe (4 u64) of
//   h(t) for step t+1 BEFORE the x-MFMA (order pinned by sched_barrier).
//   The loop head checks the prefetched values; on full tag match the
//   spin is skipped entirely — one LLC RTT hides under ~480cy of x-MFMA.
//   On miss, the unchanged R11 spin takes over (liveness identical).
// Transport unchanged (proven R4-R11): SELF-DESCRIBING TAGGED DATA at
// LLC — bit14/bit30 of each packed (hi,lo) bf16 dword carry a 2-bit step
// tag (|h|<=1 makes those bits provably 0); parity double-buffer; 0xFF
// init = tag 3 never matches first uses.
// bf16 3-split MFMA (hi/lo) both GEMMs: absmax ~3.9e-3 (proven R1-R11).

#define TT 512
#define BB 64
#define DD 512
#define HH 512
#define NWG 256
#define NTHR 512
#define GR 8

typedef short short8 __attribute__((ext_vector_type(8)));
typedef float f32x4 __attribute__((ext_vector_type(4)));

__device__ __forceinline__ uint16_t bf16_rne(float f) {
  uint32_t u = __float_as_uint(f);
  u += 0x7fffu + ((u >> 16) & 1u);
  return (uint16_t)(u >> 16);
}

__device__ __forceinline__ void split2(float f, uint16_t &hi, uint16_t &lo) {
  uint16_t h = bf16_rne(f);
  hi = h;
  lo = bf16_rne(f - __uint_as_float(((uint32_t)h) << 16));
}

__device__ __forceinline__ float sigf(float v) { return 1.0f / (1.0f + __expf(-v)); }
__device__ __forceinline__ float tanh_(float v) {
  return 1.0f - 2.0f / (__expf(2.0f * v) + 1.0f);
}

// Build MFMA B-fragment buffer from W [2048][512] (row-major, k contiguous).
// B-frag lane layout for mfma_f32_16x16x32_bf16: col = lane&15,
// k = ks*32 + (lane>>4)*8 + j (8 contiguous k per lane).
__global__ void build_frags(const float* __restrict__ W, uint32_t* __restrict__ frag) {
  const int tid = blockIdx.x * 256 + threadIdx.x;   // 0..131071
  const int lane = tid & 63;
  const int ks = (tid >> 6) & 15;
  const int nblk = tid >> 10;                        // 0..127
  const int col = nblk * 16 + (lane & 15);
  const int k0 = ks * 32 + ((lane >> 4) << 3);
  const float* src = W + (size_t)col * 512 + k0;
  float4 a = *(const float4*)(src);
  float4 b = *(const float4*)(src + 4);
  float v[8] = {a.x, a.y, a.z, a.w, b.x, b.y, b.z, b.w};
  uint32_t hw[4], lw[4];
#pragma unroll
  for (int j = 0; j < 4; ++j) {
    uint16_t h0, l0, h1, l1;
    split2(v[2 * j], h0, l0);
    split2(v[2 * j + 1], h1, l1);
    hw[j] = (uint32_t)h0 | ((uint32_t)h1 << 16);
    lw[j] = (uint32_t)l0 | ((uint32_t)l1 << 16);
  }
  uint4* dst = (uint4*)(frag + (size_t)tid * 8);
  dst[0] = make_uint4(hw[0], hw[1], hw[2], hw[3]);
  dst[1] = make_uint4(lw[0], lw[1], lw[2], lw[3]);
}

__global__ __launch_bounds__(NTHR, 2) void lstm8(
    const float* __restrict__ x, const int* __restrict__ len,
    const float* __restrict__ bias, const uint32_t* __restrict__ fragWx,
    const uint32_t* __restrict__ fragWh, uint32_t* __restrict__ h_pair,
    float* __restrict__ out) {
  const int tid = threadIdx.x;
  const int lane = tid & 63;
  const int wave = tid >> 6;      // 0..7
  const int gp = wave >> 1;       // gate 0..3 (i,f,c,o)
  const int kh = wave & 1;        // K half (cols kh*256 .. kh*256+255)
  const int group = blockIdx.x & 7;
  const int jblk = blockIdx.x >> 3;   // 0..31
  const int b0 = group * GR;
  const int j0 = jblk << 4;
  uint32_t* hbase = h_pair + (size_t)group * 2 * (GR * HH);

  __shared__ uint16_t HAH[2][GR * 512];   // 16 KB  h tile hi, parity dbuf
  __shared__ uint16_t HAL[2][GR * 512];   // 16 KB  h tile lo
  __shared__ uint16_t XH[2][GR * 512];    // 16 KB  x tile hi, parity dbuf
  __shared__ uint16_t XL[2][GR * 512];    // 16 KB  x tile lo
  __shared__ float ex[8][GR][16];         // 4 KB
  __shared__ float c_st[GR][16];
  __shared__ float h_st[GR][16];
  __shared__ float bias_l[4][16];
  __shared__ int len_l[GR];
  __shared__ uint32_t hcnt[2];            // per-half generation counters

  if (tid < 2) hcnt[tid] = 0u;
  if (tid < GR * 16) {
    c_st[tid >> 4][tid & 15] = 0.0f;
    h_st[tid >> 4][tid & 15] = 0.0f;
  }
  if (tid < 64) bias_l[tid >> 4][tid & 15] = bias[(size_t)(tid >> 4) * HH + j0 + (tid & 15)];
  if (tid < GR) len_l[tid] = len[b0 + tid];

  // Persistent B fragments: this wave's gate, this jblk, its K half.
  short8 bxh[8], bxl[8], bhh[8], bhl[8];
  {
    const int nblk = gp * 32 + jblk;
#pragma unroll
    for (int ksl = 0; ksl < 8; ++ksl) {
      const size_t idx = ((size_t)(nblk * 16 + kh * 8 + ksl) * 64 + lane) * 8;
      bxh[ksl] = __builtin_bit_cast(short8, *(const uint4*)(fragWx + idx));
      bxl[ksl] = __builtin_bit_cast(short8, *(const uint4*)(fragWx + idx + 4));
      bhh[ksl] = __builtin_bit_cast(short8, *(const uint4*)(fragWh + idx));
      bhl[ksl] = __builtin_bit_cast(short8, *(const uint4*)(fragWh + idx + 4));
    }
  }

  // A-frag addressing: row = (lane&7) (MFMA M rows 8-15 duplicate 0-7; their
  // C rows are discarded). 16B chunk = (lane>>4)*16, XOR swizzle row<<4.
  const int arow = lane & 7;
  const int achk = (lane >> 4) << 4;
  const int axr = arow << 4;

  // Poll slice (K-half split): q in [0,256) within this wave's half.
  const int q = ((wave >> 1) << 6) | lane;   // (wave/2)*64 + lane
  const int prow = q >> 5;                   // 0..7
  const int pch = q & 31;                    // 16B chunk within the half

  // Per-parity poll pointers (fixed addresses).
  const unsigned long long* pb0 =
      (const unsigned long long*)(hbase) + prow * 256 + pch * 4 + (kh ? 128 : 0);
  const unsigned long long* pb1 = pb0 + (GR * HH) / 2;   // parity-1 buffer

  f32x4 hh = {0.f, 0.f, 0.f, 0.f}, lh = {0.f, 0.f, 0.f, 0.f}, hl = {0.f, 0.f, 0.f, 0.f};
  float4 xp[2];
  uint64_t pw0 = 0, pw1 = 0, pw2 = 0, pw3 = 0;   // prefetched probe

  const uint64_t MK2 = 0x4000400040004000ull;
  const uint32_t CM = ~0x40004000u;

#define LOAD_XP(tt)                                                            \
  _Pragma("unroll") for (int i = 0; i < 2; ++i) {                              \
    const int flat4 = i * 2048 + tid * 4;                                      \
    const int row = flat4 >> 9;                                                \
    const int col = flat4 & 511;                                               \
    xp[i] = *(const float4*)(x + ((size_t)(tt) * BB + b0 + row) * DD + col);   \
  }

#define STAGE_XP(PB)                                                           \
  _Pragma("unroll") for (int i = 0; i < 2; ++i) {                              \
    const int flat4 = i * 2048 + tid * 4;                                      \
    const int row = flat4 >> 9;                                                \
    const int col = flat4 & 511;                                               \
    uint16_t h0, l0, h1, l1, h2, l2, h3, l3;                                   \
    split2(xp[i].x, h0, l0);                                                   \
    split2(xp[i].y, h1, l1);                                                   \
    split2(xp[i].z, h2, l2);                                                   \
    split2(xp[i].w, h3, l3);                                                   \
    const uint32_t hw0 = (uint32_t)h0 | ((uint32_t)h1 << 16);                  \
    const uint32_t hw1 = (uint32_t)h2 | ((uint32_t)h3 << 16);                  \
    const uint32_t lw0 = (uint32_t)l0 | ((uint32_t)l1 << 16);                  \
    const uint32_t lw1 = (uint32_t)l2 | ((uint32_t)l3 << 16);                  \
    const int off = row * 1024 + ((col * 2) ^ (row << 4));                     \
    *(uint2*)((char*)XH[PB] + off) = make_uint2(hw0, hw1);                     \
    *(uint2*)((char*)XL[PB] + off) = make_uint2(lw0, lw1);                     \
  }

#define X_MFMA(PB)                                                             \
  hh = (f32x4){0.f, 0.f, 0.f, 0.f};                                           \
  lh = (f32x4){0.f, 0.f, 0.f, 0.f};                                           \
  hl = (f32x4){0.f, 0.f, 0.f, 0.f};                                           \
  {                                                                            \
    const char* rH = (const char*)XH[PB] + arow * 1024;                        \
    const char* rL = (const char*)XL[PB] + arow * 1024;                        \
    _Pragma("unroll") for (int ksl = 0; ksl < 8; ++ksl) {                      \
      const int off = ((kh * 8 + ksl) * 64 + achk) ^ axr;                      \
      short8 ah = *(const short8*)(rH + off);                                  \
      short8 al = *(const short8*)(rL + off);                                  \
      hh = __builtin_amdgcn_mfma_f32_16x16x32_bf16(ah, bxh[ksl], hh, 0, 0, 0); \
      lh = __builtin_amdgcn_mfma_f32_16x16x32_bf16(al, bxh[ksl], lh, 0, 0, 0); \
      hl = __builtin_amdgcn_mfma_f32_16x16x32_bf16(ah, bxl[ksl], hl, 0, 0, 0); \
    }                                                                          \
  }

  // ---- prologue: acc = xproj(x_0); XB[1] <- x_1; xp <- x_2 ----
  LOAD_XP(0);
  __syncthreads();   // init (c_st, bias_l, len_l, hcnt) complete
  STAGE_XP(0);
  __syncthreads();   // XB[0] = x_0 staged
  X_MFMA(0);         // acc = xproj(x_0)
  LOAD_XP(1);
  STAGE_XP(1);       // XB[1] = x_1 (consumed at tail(0), after S1(0))
  LOAD_XP(2);

  uint32_t htg = 0;  // half-barrier generation target

  for (int t = 0; t < TT; ++t) {
    const int rbuf = t & 1;
    const int wbuf = rbuf ^ 1;

    if (t > 0) {
      // --- check prefetched probe; spin only if stale (unchanged R11) ---
      const uint32_t tg = (((uint32_t)(t - 1)) >> 1) & 3u;
      const uint32_t Ed = ((tg & 1u) << 14) | ((tg >> 1) << 30);
      const uint64_t EX2 = ((uint64_t)Ed << 32) | Ed;
      const unsigned long long* pb = rbuf ? pb1 : pb0;
      uint64_t w0 = pw0, w1 = pw1, w2 = pw2, w3 = pw3;
      uint64_t bad = (((w0 ^ EX2) | (w1 ^ EX2) | (w2 ^ EX2) | (w3 ^ EX2)) & MK2);
      while (bad != 0ull) {
        w0 = __hip_atomic_load(pb + 0, __ATOMIC_RELAXED, __HIP_MEMORY_SCOPE_AGENT);
        w1 = __hip_atomic_load(pb + 1, __ATOMIC_RELAXED, __HIP_MEMORY_SCOPE_AGENT);
        w2 = __hip_atomic_load(pb + 2, __ATOMIC_RELAXED, __HIP_MEMORY_SCOPE_AGENT);
        w3 = __hip_atomic_load(pb + 3, __ATOMIC_RELAXED, __HIP_MEMORY_SCOPE_AGENT);
        bad = (((w0 ^ EX2) | (w1 ^ EX2) | (w2 ^ EX2) | (w3 ^ EX2)) & MK2);
      }

      // --- unpack into parity h-tile, own half only ---
      // Safe: this region's last readers were this half's waves at t-2,
      // behind the t-2 half-barrier and two S1 barriers.
      {
        uint32_t d0 = (uint32_t)w0 & CM, d1 = (uint32_t)(w0 >> 32) & CM;
        uint32_t d2 = (uint32_t)w1 & CM, d3 = (uint32_t)(w1 >> 32) & CM;
        uint32_t d4 = (uint32_t)w2 & CM, d5 = (uint32_t)(w2 >> 32) & CM;
        uint32_t d6 = (uint32_t)w3 & CM, d7 = (uint32_t)(w3 >> 32) & CM;
        const uint32_t hi0 = (d0 & 0xFFFFu) | (d1 << 16);
        const uint32_t lo0 = (d0 >> 16) | (d1 & 0xFFFF0000u);
        const uint32_t hi1 = (d2 & 0xFFFFu) | (d3 << 16);
        const uint32_t lo1 = (d2 >> 16) | (d3 & 0xFFFF0000u);
        const uint32_t hi2 = (d4 & 0xFFFFu) | (d5 << 16);
        const uint32_t lo2 = (d4 >> 16) | (d5 & 0xFFFF0000u);
        const uint32_t hi3 = (d6 & 0xFFFFu) | (d7 << 16);
        const uint32_t lo3 = (d6 >> 16) | (d7 & 0xFFFF0000u);
        const int woff = prow * 1024 + ((pch * 16 + kh * 512) ^ (prow << 4));
        *(uint4*)((char*)HAH[rbuf] + woff) = make_uint4(hi0, hi1, hi2, hi3);
        *(uint4*)((char*)HAL[rbuf] + woff) = make_uint4(lo0, lo1, lo2, lo3);
      }

      // --- 4-wave half barrier (generation-counted, R8-proven pattern) ---
      htg += 4;
      if (lane == 0)
        __hip_atomic_fetch_add(&hcnt[kh], 1u, __ATOMIC_ACQ_REL,
                               __HIP_MEMORY_SCOPE_WORKGROUP);
      while (__hip_atomic_load(&hcnt[kh], __ATOMIC_ACQUIRE,
                               __HIP_MEMORY_SCOPE_WORKGROUP) < htg) {
      }
      asm volatile("" ::: "memory");

      // --- h MFMA on own K half (accumulates onto x-projection) ---
      {
        const char* rowH = (const char*)HAH[rbuf] + arow * 1024;
        const char* rowL = (const char*)HAL[rbuf] + arow * 1024;
#pragma unroll
        for (int ksl = 0; ksl < 8; ++ksl) {
          const int off = ((kh * 8 + ksl) * 64 + achk) ^ axr;
          short8 ah = *(const short8*)(rowH + off);
          short8 al = *(const short8*)(rowL + off);
          hh = __builtin_amdgcn_mfma_f32_16x16x32_bf16(ah, bhh[ksl], hh, 0, 0, 0);
          lh = __builtin_amdgcn_mfma_f32_16x16x32_bf16(al, bhh[ksl], lh, 0, 0, 0);
          hl = __builtin_amdgcn_mfma_f32_16x16x32_bf16(ah, bhl[ksl], hl, 0, 0, 0);
        }
      }
    }

    // --- exchange partial preacts (C rows 0-7 only) ---
    {
      const int crow = (lane >> 4) << 2;
      const int ccol = lane & 15;
      if (crow < GR) {
#pragma unroll
        for (int r = 0; r < 4; ++r) ex[wave][crow + r][ccol] = hh[r] + lh[r] + hl[r];
      }
    }
    __syncthreads();   // S1: ex ready (also separates x-tile stage/consume)

    // --- cell update; EARLY tagged h store, then out/state ---
    if (tid < GR * 16) {
      const int brow = tid >> 4;
      const int jc = tid & 15;
      const float p0 = ex[0][brow][jc] + ex[1][brow][jc] + bias_l[0][jc];
      const float p1 = ex[2][brow][jc] + ex[3][brow][jc] + bias_l[1][jc];
      const float p2 = ex[4][brow][jc] + ex[5][brow][jc] + bias_l[2][jc];
      const float p3 = ex[6][brow][jc] + ex[7][brow][jc] + bias_l[3][jc];
      const float ig = sigf(p0);
      const float fg = sigf(p1);
      const float cc = tanh_(p2);
      const float og = sigf(p3);
      const float co = c_st[brow][jc];
      const float ct = fg * co + ig * cc;
      const float ht = og * tanh_(ct);
      const bool m = (t < len_l[brow]);
      const float cn = m ? ct : co;
      const float hn = m ? ht : h_st[brow][jc];
      // early store: visibility to the 31 sibling WGs starts NOW
      uint16_t ph, pl;
      split2(hn, ph, pl);   // |hn| <= 1 -> bit14 of both halves = 0
      const uint32_t tagw = (((uint32_t)t) >> 1) & 3u;
      const uint32_t TB = ((tagw & 1u) << 14) | ((tagw >> 1) << 30);
      __hip_atomic_store(hbase + (size_t)wbuf * (GR * HH) + brow * HH + j0 + jc,
                         ((uint32_t)ph | ((uint32_t)pl << 16)) | TB,
                         __ATOMIC_RELAXED, __HIP_MEMORY_SCOPE_AGENT);
      out[((size_t)t * BB + b0 + brow) * HH + j0 + jc] = m ? ht : 0.0f;
      c_st[brow][jc] = cn;
      h_st[brow][jc] = hn;
    }

    if (t + 1 < TT) {
      STAGE_XP(rbuf);    // XB[t&1] <- x_{t+2} (read was at tail(t-1), behind S1)
      // --- poll prefetch for step t+1: issue first probe BEFORE x-MFMA ---
      {
        const unsigned long long* pn = wbuf ? pb1 : pb0;
        pw0 = __hip_atomic_load(pn + 0, __ATOMIC_RELAXED, __HIP_MEMORY_SCOPE_AGENT);
        pw1 = __hip_atomic_load(pn + 1, __ATOMIC_RELAXED, __HIP_MEMORY_SCOPE_AGENT);
        pw2 = __hip_atomic_load(pn + 2, __ATOMIC_RELAXED, __HIP_MEMORY_SCOPE_AGENT);
        pw3 = __hip_atomic_load(pn + 3, __ATOMIC_RELAXED, __HIP_MEMORY_SCOPE_AGENT);
      }
      __builtin_amdgcn_sched_barrier(0);   // pin probe issue before the MFMAs
      X_MFMA(wbuf);      // acc = xproj(x_{t+1}); probe RTT hides under this
      LOAD_XP(min(t + 3, TT - 1));
    }
  }
#undef LOAD_XP
#undef STAGE_XP
#undef X_MFMA
}

extern "C" void kernel_launch(void* const* d_in, const int* in_sizes, int n_in,
                              void* d_out, int out_size, void* d_ws, size_t ws_size,
                              hipStream_t stream) {
  const float* x = (const float*)d_in[0];
  const int* len = (const int*)d_in[1];
  const float* Wx = (const float*)d_in[2];    // [2048][512]
  const float* Wh = (const float*)d_in[3];    // [2048][512]
  const float* bias = (const float*)d_in[4];  // [2048]
  float* out = (float*)d_out;

  const size_t FRAG_DW = (size_t)128 * 16 * 64 * 8;   // 4 MB each
  const size_t HP_DW = (size_t)8 * 2 * GR * HH;        // 256 KB
  uint32_t* fragWx = (uint32_t*)d_ws;
  uint32_t* fragWh = fragWx + FRAG_DW;
  uint32_t* h_pair = fragWh + FRAG_DW;
  // total ~8.5 MB; ws proven >= 10.75 MB (R7's lstm3 ran).

  // 0xFF -> tag bits = 3 in every dword: never matches the first expected
  // tags and is overwritten >=2x before tag 3 recurs.
  hipMemsetAsync(h_pair, 0xFF, HP_DW * 4, stream);

  build_frags<<<dim3(512), dim3(256), 0, stream>>>(Wx, fragWx);
  build_frags<<<dim3(512), dim3(256), 0, stream>>>(Wh, fragWh);

  void* args[] = {(void*)&x,      (void*)&len,    (void*)&bias, (void*)&fragWx,
                  (void*)&fragWh, (void*)&h_pair, (void*)&out};
  hipLaunchCooperativeKernel((void*)lstm8, dim3(NWG), dim3(NTHR), args, 0, stream);
}

// Round 13
// 1456.180 us; speedup vs baseline: 1.2521x; 1.2521x over previous
//
#include <hip/hip_runtime.h>
#include <stdint.h>

// LSTM (packed sequence) on MI355X — round 13.
// T=512, B=64, D=512, H=512. out[t,b,:] = masked h_t.
//
// R11 base (best: 256 WGs = 8 groups x 32 jblk, GR=8, 2 WGs/CU, K-HALF
// SPLIT tagged LLC poll + 4-wave half barrier, parity h-tile, parity
// x-tile, early h-store, 1 full + 1 half barrier per step) + one change:
//   PIPELINED SPIN: the poll keeps TWO probe sets in flight (issue B
//   before checking A; reissue A before checking B). Checks land at
//   ~RTT/2 spacing instead of RTT, halving the mean detect-after-ready
//   delay. First-detect path identical to R11 (check A waits vmcnt(4)).
//   R12's tail-prefetch is REVERTED (probes were issued before producers
//   plausibly stored -> always stale; sched_barrier broke tail sched).
// Transport unchanged (proven R4-R12): SELF-DESCRIBING TAGGED DATA at
// LLC — bit14/bit30 of each packed (hi,lo) bf16 dword carry a 2-bit step
// tag (|h|<=1 makes those bits provably 0); parity double-buffer; 0xFF
// init = tag 3 never matches first uses.
// bf16 3-split MFMA (hi/lo) both GEMMs: absmax ~3.9e-3 (proven R1-R12).

#define TT 512
#define BB 64
#define DD 512
#define HH 512
#define NWG 256
#define NTHR 512
#define GR 8

typedef short short8 __attribute__((ext_vector_type(8)));
typedef float f32x4 __attribute__((ext_vector_type(4)));

__device__ __forceinline__ uint16_t bf16_rne(float f) {
  uint32_t u = __float_as_uint(f);
  u += 0x7fffu + ((u >> 16) & 1u);
  return (uint16_t)(u >> 16);
}

__device__ __forceinline__ void split2(float f, uint16_t &hi, uint16_t &lo) {
  uint16_t h = bf16_rne(f);
  hi = h;
  lo = bf16_rne(f - __uint_as_float(((uint32_t)h) << 16));
}

__device__ __forceinline__ float sigf(float v) { return 1.0f / (1.0f + __expf(-v)); }
__device__ __forceinline__ float tanh_(float v) {
  return 1.0f - 2.0f / (__expf(2.0f * v) + 1.0f);
}

// Build MFMA B-fragment buffer from W [2048][512] (row-major, k contiguous).
// B-frag lane layout for mfma_f32_16x16x32_bf16: col = lane&15,
// k = ks*32 + (lane>>4)*8 + j (8 contiguous k per lane).
__global__ void build_frags(const float* __restrict__ W, uint32_t* __restrict__ frag) {
  const int tid = blockIdx.x * 256 + threadIdx.x;   // 0..131071
  const int lane = tid & 63;
  const int ks = (tid >> 6) & 15;
  const int nblk = tid >> 10;                        // 0..127
  const int col = nblk * 16 + (lane & 15);
  const int k0 = ks * 32 + ((lane >> 4) << 3);
  const float* src = W + (size_t)col * 512 + k0;
  float4 a = *(const float4*)(src);
  float4 b = *(const float4*)(src + 4);
  float v[8] = {a.x, a.y, a.z, a.w, b.x, b.y, b.z, b.w};
  uint32_t hw[4], lw[4];
#pragma unroll
  for (int j = 0; j < 4; ++j) {
    uint16_t h0, l0, h1, l1;
    split2(v[2 * j], h0, l0);
    split2(v[2 * j + 1], h1, l1);
    hw[j] = (uint32_t)h0 | ((uint32_t)h1 << 16);
    lw[j] = (uint32_t)l0 | ((uint32_t)l1 << 16);
  }
  uint4* dst = (uint4*)(frag + (size_t)tid * 8);
  dst[0] = make_uint4(hw[0], hw[1], hw[2], hw[3]);
  dst[1] = make_uint4(lw[0], lw[1], lw[2], lw[3]);
}

__global__ __launch_bounds__(NTHR, 2) void lstm9(
    const float* __restrict__ x, const int* __restrict__ len,
    const float* __restrict__ bias, const uint32_t* __restrict__ fragWx,
    const uint32_t* __restrict__ fragWh, uint32_t* __restrict__ h_pair,
    float* __restrict__ out) {
  const int tid = threadIdx.x;
  const int lane = tid & 63;
  const int wave = tid >> 6;      // 0..7
  const int gp = wave >> 1;       // gate 0..3 (i,f,c,o)
  const int kh = wave & 1;        // K half (cols kh*256 .. kh*256+255)
  const int group = blockIdx.x & 7;
  const int jblk = blockIdx.x >> 3;   // 0..31
  const int b0 = group * GR;
  const int j0 = jblk << 4;
  uint32_t* hbase = h_pair + (size_t)group * 2 * (GR * HH);

  __shared__ uint16_t HAH[2][GR * 512];   // 16 KB  h tile hi, parity dbuf
  __shared__ uint16_t HAL[2][GR * 512];   // 16 KB  h tile lo
  __shared__ uint16_t XH[2][GR * 512];    // 16 KB  x tile hi, parity dbuf
  __shared__ uint16_t XL[2][GR * 512];    // 16 KB  x tile lo
  __shared__ float ex[8][GR][16];         // 4 KB
  __shared__ float c_st[GR][16];
  __shared__ float h_st[GR][16];
  __shared__ float bias_l[4][16];
  __shared__ int len_l[GR];
  __shared__ uint32_t hcnt[2];            // per-half generation counters

  if (tid < 2) hcnt[tid] = 0u;
  if (tid < GR * 16) {
    c_st[tid >> 4][tid & 15] = 0.0f;
    h_st[tid >> 4][tid & 15] = 0.0f;
  }
  if (tid < 64) bias_l[tid >> 4][tid & 15] = bias[(size_t)(tid >> 4) * HH + j0 + (tid & 15)];
  if (tid < GR) len_l[tid] = len[b0 + tid];

  // Persistent B fragments: this wave's gate, this jblk, its K half.
  short8 bxh[8], bxl[8], bhh[8], bhl[8];
  {
    const int nblk = gp * 32 + jblk;
#pragma unroll
    for (int ksl = 0; ksl < 8; ++ksl) {
      const size_t idx = ((size_t)(nblk * 16 + kh * 8 + ksl) * 64 + lane) * 8;
      bxh[ksl] = __builtin_bit_cast(short8, *(const uint4*)(fragWx + idx));
      bxl[ksl] = __builtin_bit_cast(short8, *(const uint4*)(fragWx + idx + 4));
      bhh[ksl] = __builtin_bit_cast(short8, *(const uint4*)(fragWh + idx));
      bhl[ksl] = __builtin_bit_cast(short8, *(const uint4*)(fragWh + idx + 4));
    }
  }

  // A-frag addressing: row = (lane&7) (MFMA M rows 8-15 duplicate 0-7; their
  // C rows are discarded). 16B chunk = (lane>>4)*16, XOR swizzle row<<4.
  const int arow = lane & 7;
  const int achk = (lane >> 4) << 4;
  const int axr = arow << 4;

  // Poll slice (K-half split): q in [0,256) within this wave's half.
  const int q = ((wave >> 1) << 6) | lane;   // (wave/2)*64 + lane
  const int prow = q >> 5;                   // 0..7
  const int pch = q & 31;                    // 16B chunk within the half

  f32x4 hh = {0.f, 0.f, 0.f, 0.f}, lh = {0.f, 0.f, 0.f, 0.f}, hl = {0.f, 0.f, 0.f, 0.f};
  float4 xp[2];

  const uint64_t MK2 = 0x4000400040004000ull;
  const uint32_t CM = ~0x40004000u;

#define LOAD_XP(tt)                                                            \
  _Pragma("unroll") for (int i = 0; i < 2; ++i) {                              \
    const int flat4 = i * 2048 + tid * 4;                                      \
    const int row = flat4 >> 9;                                                \
    const int col = flat4 & 511;                                               \
    xp[i] = *(const float4*)(x + ((size_t)(tt) * BB + b0 + row) * DD + col);   \
  }

#define STAGE_XP(PB)                                                           \
  _Pragma("unroll") for (int i = 0; i < 2; ++i) {                              \
    const int flat4 = i * 2048 + tid * 4;                                      \
    const int row = flat4 >> 9;                                                \
    const int col = flat4 & 511;                                               \
    uint16_t h0, l0, h1, l1, h2, l2, h3, l3;                                   \
    split2(xp[i].x, h0, l0);                                                   \
    split2(xp[i].y, h1, l1);                                                   \
    split2(xp[i].z, h2, l2);                                                   \
    split2(xp[i].w, h3, l3);                                                   \
    const uint32_t hw0 = (uint32_t)h0 | ((uint32_t)h1 << 16);                  \
    const uint32_t hw1 = (uint32_t)h2 | ((uint32_t)h3 << 16);                  \
    const uint32_t lw0 = (uint32_t)l0 | ((uint32_t)l1 << 16);                  \
    const uint32_t lw1 = (uint32_t)l2 | ((uint32_t)l3 << 16);                  \
    const int off = row * 1024 + ((col * 2) ^ (row << 4));                     \
    *(uint2*)((char*)XH[PB] + off) = make_uint2(hw0, hw1);                     \
    *(uint2*)((char*)XL[PB] + off) = make_uint2(lw0, lw1);                     \
  }

#define X_MFMA(PB)                                                             \
  hh = (f32x4){0.f, 0.f, 0.f, 0.f};                                           \
  lh = (f32x4){0.f, 0.f, 0.f, 0.f};                                           \
  hl = (f32x4){0.f, 0.f, 0.f, 0.f};                                           \
  {                                                                            \
    const char* rH = (const char*)XH[PB] + arow * 1024;                        \
    const char* rL = (const char*)XL[PB] + arow * 1024;                        \
    _Pragma("unroll") for (int ksl = 0; ksl < 8; ++ksl) {                      \
      const int off = ((kh * 8 + ksl) * 64 + achk) ^ axr;                      \
      short8 ah = *(const short8*)(rH + off);                                  \
      short8 al = *(const short8*)(rL + off);                                  \
      hh = __builtin_amdgcn_mfma_f32_16x16x32_bf16(ah, bxh[ksl], hh, 0, 0, 0); \
      lh = __builtin_amdgcn_mfma_f32_16x16x32_bf16(al, bxh[ksl], lh, 0, 0, 0); \
      hl = __builtin_amdgcn_mfma_f32_16x16x32_bf16(ah, bxl[ksl], hl, 0, 0, 0); \
    }                                                                          \
  }

  // ---- prologue: acc = xproj(x_0); XB[1] <- x_1; xp <- x_2 ----
  LOAD_XP(0);
  __syncthreads();   // init (c_st, bias_l, len_l, hcnt) complete
  STAGE_XP(0);
  __syncthreads();   // XB[0] = x_0 staged
  X_MFMA(0);         // acc = xproj(x_0)
  LOAD_XP(1);
  STAGE_XP(1);       // XB[1] = x_1 (consumed at tail(0), after S1(0))
  LOAD_XP(2);

  uint32_t htg = 0;  // half-barrier generation target

  for (int t = 0; t < TT; ++t) {
    const int rbuf = t & 1;
    const int wbuf = rbuf ^ 1;

    if (t > 0) {
      // --- PIPELINED spin on this wave's K-HALF of tagged h_{t-1}:
      //     two probe sets in flight -> checks at ~RTT/2 spacing ---
      const uint32_t tg = (((uint32_t)(t - 1)) >> 1) & 3u;
      const uint32_t Ed = ((tg & 1u) << 14) | ((tg >> 1) << 30);
      const uint64_t EX2 = ((uint64_t)Ed << 32) | Ed;
      const unsigned long long* pb =
          (const unsigned long long*)(hbase + (size_t)rbuf * (GR * HH)) +
          prow * 256 + pch * 4 + (kh ? 128 : 0);
      uint64_t w0, w1, w2, w3;
      {
        uint64_t a0, a1, a2, a3, b0_, b1_, b2_, b3_;
        a0 = __hip_atomic_load(pb + 0, __ATOMIC_RELAXED, __HIP_MEMORY_SCOPE_AGENT);
        a1 = __hip_atomic_load(pb + 1, __ATOMIC_RELAXED, __HIP_MEMORY_SCOPE_AGENT);
        a2 = __hip_atomic_load(pb + 2, __ATOMIC_RELAXED, __HIP_MEMORY_SCOPE_AGENT);
        a3 = __hip_atomic_load(pb + 3, __ATOMIC_RELAXED, __HIP_MEMORY_SCOPE_AGENT);
        for (;;) {
          // issue B before consuming A (stays in flight across A's check)
          b0_ = __hip_atomic_load(pb + 0, __ATOMIC_RELAXED, __HIP_MEMORY_SCOPE_AGENT);
          b1_ = __hip_atomic_load(pb + 1, __ATOMIC_RELAXED, __HIP_MEMORY_SCOPE_AGENT);
          b2_ = __hip_atomic_load(pb + 2, __ATOMIC_RELAXED, __HIP_MEMORY_SCOPE_AGENT);
          b3_ = __hip_atomic_load(pb + 3, __ATOMIC_RELAXED, __HIP_MEMORY_SCOPE_AGENT);
          if ((((a0 ^ EX2) | (a1 ^ EX2) | (a2 ^ EX2) | (a3 ^ EX2)) & MK2) == 0ull) {
            w0 = a0; w1 = a1; w2 = a2; w3 = a3;
            break;
          }
          a0 = __hip_atomic_load(pb + 0, __ATOMIC_RELAXED, __HIP_MEMORY_SCOPE_AGENT);
          a1 = __hip_atomic_load(pb + 1, __ATOMIC_RELAXED, __HIP_MEMORY_SCOPE_AGENT);
          a2 = __hip_atomic_load(pb + 2, __ATOMIC_RELAXED, __HIP_MEMORY_SCOPE_AGENT);
          a3 = __hip_atomic_load(pb + 3, __ATOMIC_RELAXED, __HIP_MEMORY_SCOPE_AGENT);
          if ((((b0_ ^ EX2) | (b1_ ^ EX2) | (b2_ ^ EX2) | (b3_ ^ EX2)) & MK2) == 0ull) {
            w0 = b0_; w1 = b1_; w2 = b2_; w3 = b3_;
            break;
          }
        }
      }

      // --- unpack into parity h-tile, own half only ---
      // Safe: this region's last readers were this half's waves at t-2,
      // behind the t-2 half-barrier and two S1 barriers.
      {
        uint32_t d0 = (uint32_t)w0 & CM, d1 = (uint32_t)(w0 >> 32) & CM;
        uint32_t d2 = (uint32_t)w1 & CM, d3 = (uint32_t)(w1 >> 32) & CM;
        uint32_t d4 = (uint32_t)w2 & CM, d5 = (uint32_t)(w2 >> 32) & CM;
        uint32_t d6 = (uint32_t)w3 & CM, d7 = (uint32_t)(w3 >> 32) & CM;
        const uint32_t hi0 = (d0 & 0xFFFFu) | (d1 << 16);
        const uint32_t lo0 = (d0 >> 16) | (d1 & 0xFFFF0000u);
        const uint32_t hi1 = (d2 & 0xFFFFu) | (d3 << 16);
        const uint32_t lo1 = (d2 >> 16) | (d3 & 0xFFFF0000u);
        const uint32_t hi2 = (d4 & 0xFFFFu) | (d5 << 16);
        const uint32_t lo2 = (d4 >> 16) | (d5 & 0xFFFF0000u);
        const uint32_t hi3 = (d6 & 0xFFFFu) | (d7 << 16);
        const uint32_t lo3 = (d6 >> 16) | (d7 & 0xFFFF0000u);
        const int woff = prow * 1024 + ((pch * 16 + kh * 512) ^ (prow << 4));
        *(uint4*)((char*)HAH[rbuf] + woff) = make_uint4(hi0, hi1, hi2, hi3);
        *(uint4*)((char*)HAL[rbuf] + woff) = make_uint4(lo0, lo1, lo2, lo3);
      }

      // --- 4-wave half barrier (generation-counted, R8-proven pattern) ---
      htg += 4;
      if (lane == 0)
        __hip_atomic_fetch_add(&hcnt[kh], 1u, __ATOMIC_ACQ_REL,
                               __HIP_MEMORY_SCOPE_WORKGROUP);
      while (__hip_atomic_load(&hcnt[kh], __ATOMIC_ACQUIRE,
                               __HIP_MEMORY_SCOPE_WORKGROUP) < htg) {
      }
      asm volatile("" ::: "memory");

      // --- h MFMA on own K half (accumulates onto x-projection) ---
      {
        const char* rowH = (const char*)HAH[rbuf] + arow * 1024;
        const char* rowL = (const char*)HAL[rbuf] + arow * 1024;
#pragma unroll
        for (int ksl = 0; ksl < 8; ++ksl) {
          const int off = ((kh * 8 + ksl) * 64 + achk) ^ axr;
          short8 ah = *(const short8*)(rowH + off);
          short8 al = *(const short8*)(rowL + off);
          hh = __builtin_amdgcn_mfma_f32_16x16x32_bf16(ah, bhh[ksl], hh, 0, 0, 0);
          lh = __builtin_amdgcn_mfma_f32_16x16x32_bf16(al, bhh[ksl], lh, 0, 0, 0);
          hl = __builtin_amdgcn_mfma_f32_16x16x32_bf16(ah, bhl[ksl], hl, 0, 0, 0);
        }
      }
    }

    // --- exchange partial preacts (C rows 0-7 only) ---
    {
      const int crow = (lane >> 4) << 2;
      const int ccol = lane & 15;
      if (crow < GR) {
#pragma unroll
        for (int r = 0; r < 4; ++r) ex[wave][crow + r][ccol] = hh[r] + lh[r] + hl[r];
      }
    }
    __syncthreads();   // S1: ex ready (also separates x-tile stage/consume)

    // --- cell update; EARLY tagged h store, then out/state ---
    if (tid < GR * 16) {
      const int brow = tid >> 4;
      const int jc = tid & 15;
      const float p0 = ex[0][brow][jc] + ex[1][brow][jc] + bias_l[0][jc];
      const float p1 = ex[2][brow][jc] + ex[3][brow][jc] + bias_l[1][jc];
      const float p2 = ex[4][brow][jc] + ex[5][brow][jc] + bias_l[2][jc];
      const float p3 = ex[6][brow][jc] + ex[7][brow][jc] + bias_l[3][jc];
      const float ig = sigf(p0);
      const float fg = sigf(p1);
      const float cc = tanh_(p2);
      const float og = sigf(p3);
      const float co = c_st[brow][jc];
      const float ct = fg * co + ig * cc;
      const float ht = og * tanh_(ct);
      const bool m = (t < len_l[brow]);
      const float cn = m ? ct : co;
      const float hn = m ? ht : h_st[brow][jc];
      // early store: visibility to the 31 sibling WGs starts NOW
      uint16_t ph, pl;
      split2(hn, ph, pl);   // |hn| <= 1 -> bit14 of both halves = 0
      const uint32_t tagw = (((uint32_t)t) >> 1) & 3u;
      const uint32_t TB = ((tagw & 1u) << 14) | ((tagw >> 1) << 30);
      __hip_atomic_store(hbase + (size_t)wbuf * (GR * HH) + brow * HH + j0 + jc,
                         ((uint32_t)ph | ((uint32_t)pl << 16)) | TB,
                         __ATOMIC_RELAXED, __HIP_MEMORY_SCOPE_AGENT);
      out[((size_t)t * BB + b0 + brow) * HH + j0 + jc] = m ? ht : 0.0f;
      c_st[brow][jc] = cn;
      h_st[brow][jc] = hn;
    }

    if (t + 1 < TT) {
      STAGE_XP(rbuf);        // XB[t&1] <- x_{t+2} (read of XB[t&1] was at
                             // tail(t-1), behind S1(t))
      X_MFMA(wbuf);          // acc = xproj(x_{t+1}) from XB[(t&1)^1],
                             // staged at tail(t-1), behind S1(t)
      LOAD_XP(min(t + 3, TT - 1));
    }
  }
#undef LOAD_XP
#undef STAGE_XP
#undef X_MFMA
}

extern "C" void kernel_launch(void* const* d_in, const int* in_sizes, int n_in,
                              void* d_out, int out_size, void* d_ws, size_t ws_size,
                              hipStream_t stream) {
  const float* x = (const float*)d_in[0];
  const int* len = (const int*)d_in[1];
  const float* Wx = (const float*)d_in[2];    // [2048][512]
  const float* Wh = (const float*)d_in[3];    // [2048][512]
  const float* bias = (const float*)d_in[4];  // [2048]
  float* out = (float*)d_out;

  const size_t FRAG_DW = (size_t)128 * 16 * 64 * 8;   // 4 MB each
  const size_t HP_DW = (size_t)8 * 2 * GR * HH;        // 256 KB
  uint32_t* fragWx = (uint32_t*)d_ws;
  uint32_t* fragWh = fragWx + FRAG_DW;
  uint32_t* h_pair = fragWh + FRAG_DW;
  // total ~8.5 MB; ws proven >= 10.75 MB (R7's lstm3 ran).

  // 0xFF -> tag bits = 3 in every dword: never matches the first expected
  // tags and is overwritten >=2x before tag 3 recurs.
  hipMemsetAsync(h_pair, 0xFF, HP_DW * 4, stream);

  build_frags<<<dim3(512), dim3(256), 0, stream>>>(Wx, fragWx);
  build_frags<<<dim3(512), dim3(256), 0, stream>>>(Wh, fragWh);

  void* args[] = {(void*)&x,      (void*)&len,    (void*)&bias, (void*)&fragWx,
                  (void*)&fragWh, (void*)&h_pair, (void*)&out};
  hipLaunchCooperativeKernel((void*)lstm9, dim3(NWG), dim3(NTHR), args, 0, stream);
}

// Round 14
// 1173.471 us; speedup vs baseline: 1.5537x; 1.2409x over previous
//
#include <hip/hip_runtime.h>
#include <stdint.h>

// LSTM (packed sequence) on MI355X — round 14 = REVERT to round 11 (best).
// T=512, B=64, D=512, H=512. out[t,b,:] = masked h_t.
//
// R11 (best measured: timing 1176 us, steady rocprof 1380 us):
//   256 WGs = 8 groups (GR=8 batch rows) x 32 jblk (16 hidden cols).
//   2 WGs/CU (TLP: one WG's x-tail overlaps the sibling's poll).
//   K-HALF SPLIT EXCHANGE: wave kh polls/unpacks only h cols
//     [kh*256, kh*256+256); each half crosses a 4-wave LDS generation
//     barrier then starts its h-MFMA immediately (two overlapping
//     max-of-16 waits instead of one max-of-32).
//   Flat 4-u64 tagged poll (empirically optimal probe shape: R8 wide,
//     R12 prefetch, R13 pipelined all regressed).
//   Parity h-tile (poll->unpack->halfbar->MFMA, no pre-unpack barrier),
//   parity x-tile (S2 barrier deleted), early tagged h-store.
//   1 full + 1 half barrier per step.
// Transport (proven R4-R13): SELF-DESCRIBING TAGGED DATA at LLC —
//   bit14/bit30 of each packed (hi,lo) bf16 dword carry a 2-bit step tag
//   (|h|<=1 makes those bits provably 0); parity double-buffer; 0xFF
//   init = tag 3 never matches first uses.
// bf16 3-split MFMA (hi/lo) both GEMMs: absmax ~3.9e-3 vs 1.89e-2 thr.
//
// Structural floor note: step ~= 3780cy @ ~1.4GHz = 960 MFMA-issue +
// ~900 VALU/barriers + ~1900 LLC store-visibility/detect/producer-jitter.
// The last term resisted: wide poll (R8), XCD-local L2 (R3/R5), WG
// specialization (R7), wave specialization (R8), prefetch (R12),
// pipelined spin (R13) all regressed; flags (R2), central barrier (R1)
// were strictly worse than tagged data.

#define TT 512
#define BB 64
#define DD 512
#define HH 512
#define NWG 256
#define NTHR 512
#define GR 8

typedef short short8 __attribute__((ext_vector_type(8)));
typedef float f32x4 __attribute__((ext_vector_type(4)));

__device__ __forceinline__ uint16_t bf16_rne(float f) {
  uint32_t u = __float_as_uint(f);
  u += 0x7fffu + ((u >> 16) & 1u);
  return (uint16_t)(u >> 16);
}

__device__ __forceinline__ void split2(float f, uint16_t &hi, uint16_t &lo) {
  uint16_t h = bf16_rne(f);
  hi = h;
  lo = bf16_rne(f - __uint_as_float(((uint32_t)h) << 16));
}

__device__ __forceinline__ float sigf(float v) { return 1.0f / (1.0f + __expf(-v)); }
__device__ __forceinline__ float tanh_(float v) {
  return 1.0f - 2.0f / (__expf(2.0f * v) + 1.0f);
}

// Build MFMA B-fragment buffer from W [2048][512] (row-major, k contiguous).
// B-frag lane layout for mfma_f32_16x16x32_bf16: col = lane&15,
// k = ks*32 + (lane>>4)*8 + j (8 contiguous k per lane).
__global__ void build_frags(const float* __restrict__ W, uint32_t* __restrict__ frag) {
  const int tid = blockIdx.x * 256 + threadIdx.x;   // 0..131071
  const int lane = tid & 63;
  const int ks = (tid >> 6) & 15;
  const int nblk = tid >> 10;                        // 0..127
  const int col = nblk * 16 + (lane & 15);
  const int k0 = ks * 32 + ((lane >> 4) << 3);
  const float* src = W + (size_t)col * 512 + k0;
  float4 a = *(const float4*)(src);
  float4 b = *(const float4*)(src + 4);
  float v[8] = {a.x, a.y, a.z, a.w, b.x, b.y, b.z, b.w};
  uint32_t hw[4], lw[4];
#pragma unroll
  for (int j = 0; j < 4; ++j) {
    uint16_t h0, l0, h1, l1;
    split2(v[2 * j], h0, l0);
    split2(v[2 * j + 1], h1, l1);
    hw[j] = (uint32_t)h0 | ((uint32_t)h1 << 16);
    lw[j] = (uint32_t)l0 | ((uint32_t)l1 << 16);
  }
  uint4* dst = (uint4*)(frag + (size_t)tid * 8);
  dst[0] = make_uint4(hw[0], hw[1], hw[2], hw[3]);
  dst[1] = make_uint4(lw[0], lw[1], lw[2], lw[3]);
}

__global__ __launch_bounds__(NTHR, 2) void lstm7(
    const float* __restrict__ x, const int* __restrict__ len,
    const float* __restrict__ bias, const uint32_t* __restrict__ fragWx,
    const uint32_t* __restrict__ fragWh, uint32_t* __restrict__ h_pair,
    float* __restrict__ out) {
  const int tid = threadIdx.x;
  const int lane = tid & 63;
  const int wave = tid >> 6;      // 0..7
  const int gp = wave >> 1;       // gate 0..3 (i,f,c,o)
  const int kh = wave & 1;        // K half (cols kh*256 .. kh*256+255)
  const int group = blockIdx.x & 7;
  const int jblk = blockIdx.x >> 3;   // 0..31
  const int b0 = group * GR;
  const int j0 = jblk << 4;
  uint32_t* hbase = h_pair + (size_t)group * 2 * (GR * HH);

  __shared__ uint16_t HAH[2][GR * 512];   // 16 KB  h tile hi, parity dbuf
  __shared__ uint16_t HAL[2][GR * 512];   // 16 KB  h tile lo
  __shared__ uint16_t XH[2][GR * 512];    // 16 KB  x tile hi, parity dbuf
  __shared__ uint16_t XL[2][GR * 512];    // 16 KB  x tile lo
  __shared__ float ex[8][GR][16];         // 4 KB
  __shared__ float c_st[GR][16];
  __shared__ float h_st[GR][16];
  __shared__ float bias_l[4][16];
  __shared__ int len_l[GR];
  __shared__ uint32_t hcnt[2];            // per-half generation counters

  if (tid < 2) hcnt[tid] = 0u;
  if (tid < GR * 16) {
    c_st[tid >> 4][tid & 15] = 0.0f;
    h_st[tid >> 4][tid & 15] = 0.0f;
  }
  if (tid < 64) bias_l[tid >> 4][tid & 15] = bias[(size_t)(tid >> 4) * HH + j0 + (tid & 15)];
  if (tid < GR) len_l[tid] = len[b0 + tid];

  // Persistent B fragments: this wave's gate, this jblk, its K half.
  short8 bxh[8], bxl[8], bhh[8], bhl[8];
  {
    const int nblk = gp * 32 + jblk;
#pragma unroll
    for (int ksl = 0; ksl < 8; ++ksl) {
      const size_t idx = ((size_t)(nblk * 16 + kh * 8 + ksl) * 64 + lane) * 8;
      bxh[ksl] = __builtin_bit_cast(short8, *(const uint4*)(fragWx + idx));
      bxl[ksl] = __builtin_bit_cast(short8, *(const uint4*)(fragWx + idx + 4));
      bhh[ksl] = __builtin_bit_cast(short8, *(const uint4*)(fragWh + idx));
      bhl[ksl] = __builtin_bit_cast(short8, *(const uint4*)(fragWh + idx + 4));
    }
  }

  // A-frag addressing: row = (lane&7) (MFMA M rows 8-15 duplicate 0-7; their
  // C rows are discarded). 16B chunk = (lane>>4)*16, XOR swizzle row<<4.
  const int arow = lane & 7;
  const int achk = (lane >> 4) << 4;
  const int axr = arow << 4;

  // Poll slice (K-half split): q in [0,256) within this wave's half.
  const int q = ((wave >> 1) << 6) | lane;   // (wave/2)*64 + lane
  const int prow = q >> 5;                   // 0..7
  const int pch = q & 31;                    // 16B chunk within the half

  f32x4 hh = {0.f, 0.f, 0.f, 0.f}, lh = {0.f, 0.f, 0.f, 0.f}, hl = {0.f, 0.f, 0.f, 0.f};
  float4 xp[2];

  const uint64_t MK2 = 0x4000400040004000ull;
  const uint32_t CM = ~0x40004000u;

#define LOAD_XP(tt)                                                            \
  _Pragma("unroll") for (int i = 0; i < 2; ++i) {                              \
    const int flat4 = i * 2048 + tid * 4;                                      \
    const int row = flat4 >> 9;                                                \
    const int col = flat4 & 511;                                               \
    xp[i] = *(const float4*)(x + ((size_t)(tt) * BB + b0 + row) * DD + col);   \
  }

#define STAGE_XP(PB)                                                           \
  _Pragma("unroll") for (int i = 0; i < 2; ++i) {                              \
    const int flat4 = i * 2048 + tid * 4;                                      \
    const int row = flat4 >> 9;                                                \
    const int col = flat4 & 511;                                               \
    uint16_t h0, l0, h1, l1, h2, l2, h3, l3;                                   \
    split2(xp[i].x, h0, l0);                                                   \
    split2(xp[i].y, h1, l1);                                                   \
    split2(xp[i].z, h2, l2);                                                   \
    split2(xp[i].w, h3, l3);                                                   \
    const uint32_t hw0 = (uint32_t)h0 | ((uint32_t)h1 << 16);                  \
    const uint32_t hw1 = (uint32_t)h2 | ((uint32_t)h3 << 16);                  \
    const uint32_t lw0 = (uint32_t)l0 | ((uint32_t)l1 << 16);                  \
    const uint32_t lw1 = (uint32_t)l2 | ((uint32_t)l3 << 16);                  \
    const int off = row * 1024 + ((col * 2) ^ (row << 4));                     \
    *(uint2*)((char*)XH[PB] + off) = make_uint2(hw0, hw1);                     \
    *(uint2*)((char*)XL[PB] + off) = make_uint2(lw0, lw1);                     \
  }

#define X_MFMA(PB)                                                             \
  hh = (f32x4){0.f, 0.f, 0.f, 0.f};                                           \
  lh = (f32x4){0.f, 0.f, 0.f, 0.f};                                           \
  hl = (f32x4){0.f, 0.f, 0.f, 0.f};                                           \
  {                                                                            \
    const char* rH = (const char*)XH[PB] + arow * 1024;                        \
    const char* rL = (const char*)XL[PB] + arow * 1024;                        \
    _Pragma("unroll") for (int ksl = 0; ksl < 8; ++ksl) {                      \
      const int off = ((kh * 8 + ksl) * 64 + achk) ^ axr;                      \
      short8 ah = *(const short8*)(rH + off);                                  \
      short8 al = *(const short8*)(rL + off);                                  \
      hh = __builtin_amdgcn_mfma_f32_16x16x32_bf16(ah, bxh[ksl], hh, 0, 0, 0); \
      lh = __builtin_amdgcn_mfma_f32_16x16x32_bf16(al, bxh[ksl], lh, 0, 0, 0); \
      hl = __builtin_amdgcn_mfma_f32_16x16x32_bf16(ah, bxl[ksl], hl, 0, 0, 0); \
    }                                                                          \
  }

  // ---- prologue: acc = xproj(x_0); XB[1] <- x_1; xp <- x_2 ----
  LOAD_XP(0);
  __syncthreads();   // init (c_st, bias_l, len_l, hcnt) complete
  STAGE_XP(0);
  __syncthreads();   // XB[0] = x_0 staged
  X_MFMA(0);         // acc = xproj(x_0)
  LOAD_XP(1);
  STAGE_XP(1);       // XB[1] = x_1 (consumed at tail(0), after S1(0))
  LOAD_XP(2);

  uint32_t htg = 0;  // half-barrier generation target

  for (int t = 0; t < TT; ++t) {
    const int rbuf = t & 1;
    const int wbuf = rbuf ^ 1;

    if (t > 0) {
      // --- flat poll of this wave's K-HALF of tagged h_{t-1} ---
      const uint32_t tg = (((uint32_t)(t - 1)) >> 1) & 3u;
      const uint32_t Ed = ((tg & 1u) << 14) | ((tg >> 1) << 30);
      const uint64_t EX2 = ((uint64_t)Ed << 32) | Ed;
      const unsigned long long* pb =
          (const unsigned long long*)(hbase + (size_t)rbuf * (GR * HH)) +
          prow * 256 + pch * 4 + (kh ? 128 : 0);
      uint64_t w0, w1, w2, w3;
      for (;;) {
        w0 = __hip_atomic_load(pb + 0, __ATOMIC_RELAXED, __HIP_MEMORY_SCOPE_AGENT);
        w1 = __hip_atomic_load(pb + 1, __ATOMIC_RELAXED, __HIP_MEMORY_SCOPE_AGENT);
        w2 = __hip_atomic_load(pb + 2, __ATOMIC_RELAXED, __HIP_MEMORY_SCOPE_AGENT);
        w3 = __hip_atomic_load(pb + 3, __ATOMIC_RELAXED, __HIP_MEMORY_SCOPE_AGENT);
        const uint64_t bad =
            (((w0 ^ EX2) | (w1 ^ EX2) | (w2 ^ EX2) | (w3 ^ EX2)) & MK2);
        if (bad == 0ull) break;
      }

      // --- unpack into parity h-tile, own half only ---
      // Safe: this region's last readers were this half's waves at t-2,
      // behind the t-2 half-barrier and two S1 barriers.
      {
        uint32_t d0 = (uint32_t)w0 & CM, d1 = (uint32_t)(w0 >> 32) & CM;
        uint32_t d2 = (uint32_t)w1 & CM, d3 = (uint32_t)(w1 >> 32) & CM;
        uint32_t d4 = (uint32_t)w2 & CM, d5 = (uint32_t)(w2 >> 32) & CM;
        uint32_t d6 = (uint32_t)w3 & CM, d7 = (uint32_t)(w3 >> 32) & CM;
        const uint32_t hi0 = (d0 & 0xFFFFu) | (d1 << 16);
        const uint32_t lo0 = (d0 >> 16) | (d1 & 0xFFFF0000u);
        const uint32_t hi1 = (d2 & 0xFFFFu) | (d3 << 16);
        const uint32_t lo1 = (d2 >> 16) | (d3 & 0xFFFF0000u);
        const uint32_t hi2 = (d4 & 0xFFFFu) | (d5 << 16);
        const uint32_t lo2 = (d4 >> 16) | (d5 & 0xFFFF0000u);
        const uint32_t hi3 = (d6 & 0xFFFFu) | (d7 << 16);
        const uint32_t lo3 = (d6 >> 16) | (d7 & 0xFFFF0000u);
        const int woff = prow * 1024 + ((pch * 16 + kh * 512) ^ (prow << 4));
        *(uint4*)((char*)HAH[rbuf] + woff) = make_uint4(hi0, hi1, hi2, hi3);
        *(uint4*)((char*)HAL[rbuf] + woff) = make_uint4(lo0, lo1, lo2, lo3);
      }

      // --- 4-wave half barrier (generation-counted, R8-proven pattern) ---
      htg += 4;
      if (lane == 0)
        __hip_atomic_fetch_add(&hcnt[kh], 1u, __ATOMIC_ACQ_REL,
                               __HIP_MEMORY_SCOPE_WORKGROUP);
      while (__hip_atomic_load(&hcnt[kh], __ATOMIC_ACQUIRE,
                               __HIP_MEMORY_SCOPE_WORKGROUP) < htg) {
      }
      asm volatile("" ::: "memory");

      // --- h MFMA on own K half (accumulates onto x-projection) ---
      {
        const char* rowH = (const char*)HAH[rbuf] + arow * 1024;
        const char* rowL = (const char*)HAL[rbuf] + arow * 1024;
#pragma unroll
        for (int ksl = 0; ksl < 8; ++ksl) {
          const int off = ((kh * 8 + ksl) * 64 + achk) ^ axr;
          short8 ah = *(const short8*)(rowH + off);
          short8 al = *(const short8*)(rowL + off);
          hh = __builtin_amdgcn_mfma_f32_16x16x32_bf16(ah, bhh[ksl], hh, 0, 0, 0);
          lh = __builtin_amdgcn_mfma_f32_16x16x32_bf16(al, bhh[ksl], lh, 0, 0, 0);
          hl = __builtin_amdgcn_mfma_f32_16x16x32_bf16(ah, bhl[ksl], hl, 0, 0, 0);
        }
      }
    }

    // --- exchange partial preacts (C rows 0-7 only) ---
    {
      const int crow = (lane >> 4) << 2;
      const int ccol = lane & 15;
      if (crow < GR) {
#pragma unroll
        for (int r = 0; r < 4; ++r) ex[wave][crow + r][ccol] = hh[r] + lh[r] + hl[r];
      }
    }
    __syncthreads();   // S1: ex ready (also separates x-tile stage/consume)

    // --- cell update; EARLY tagged h store, then out/state ---
    if (tid < GR * 16) {
      const int brow = tid >> 4;
      const int jc = tid & 15;
      const float p0 = ex[0][brow][jc] + ex[1][brow][jc] + bias_l[0][jc];
      const float p1 = ex[2][brow][jc] + ex[3][brow][jc] + bias_l[1][jc];
      const float p2 = ex[4][brow][jc] + ex[5][brow][jc] + bias_l[2][jc];
      const float p3 = ex[6][brow][jc] + ex[7][brow][jc] + bias_l[3][jc];
      const float ig = sigf(p0);
      const float fg = sigf(p1);
      const float cc = tanh_(p2);
      const float og = sigf(p3);
      const float co = c_st[brow][jc];
      const float ct = fg * co + ig * cc;
      const float ht = og * tanh_(ct);
      const bool m = (t < len_l[brow]);
      const float cn = m ? ct : co;
      const float hn = m ? ht : h_st[brow][jc];
      // early store: visibility to the 31 sibling WGs starts NOW
      uint16_t ph, pl;
      split2(hn, ph, pl);   // |hn| <= 1 -> bit14 of both halves = 0
      const uint32_t tagw = (((uint32_t)t) >> 1) & 3u;
      const uint32_t TB = ((tagw & 1u) << 14) | ((tagw >> 1) << 30);
      __hip_atomic_store(hbase + (size_t)wbuf * (GR * HH) + brow * HH + j0 + jc,
                         ((uint32_t)ph | ((uint32_t)pl << 16)) | TB,
                         __ATOMIC_RELAXED, __HIP_MEMORY_SCOPE_AGENT);
      out[((size_t)t * BB + b0 + brow) * HH + j0 + jc] = m ? ht : 0.0f;
      c_st[brow][jc] = cn;
      h_st[brow][jc] = hn;
    }

    if (t + 1 < TT) {
      STAGE_XP(rbuf);        // XB[t&1] <- x_{t+2} (read of XB[t&1] was at
                             // tail(t-1), behind S1(t))
      X_MFMA(wbuf);          // acc = xproj(x_{t+1}) from XB[(t&1)^1],
                             // staged at tail(t-1), behind S1(t)
      LOAD_XP(min(t + 3, TT - 1));
    }
  }
#undef LOAD_XP
#undef STAGE_XP
#undef X_MFMA
}

extern "C" void kernel_launch(void* const* d_in, const int* in_sizes, int n_in,
                              void* d_out, int out_size, void* d_ws, size_t ws_size,
                              hipStream_t stream) {
  const float* x = (const float*)d_in[0];
  const int* len = (const int*)d_in[1];
  const float* Wx = (const float*)d_in[2];    // [2048][512]
  const float* Wh = (const float*)d_in[3];    // [2048][512]
  const float* bias = (const float*)d_in[4];  // [2048]
  float* out = (float*)d_out;

  const size_t FRAG_DW = (size_t)128 * 16 * 64 * 8;   // 4 MB each
  const size_t HP_DW = (size_t)8 * 2 * GR * HH;        // 256 KB
  uint32_t* fragWx = (uint32_t*)d_ws;
  uint32_t* fragWh = fragWx + FRAG_DW;
  uint32_t* h_pair = fragWh + FRAG_DW;
  // total ~8.5 MB; ws proven >= 10.75 MB (R7's lstm3 ran).

  // 0xFF -> tag bits = 3 in every dword: never matches the first expected
  // tags and is overwritten >=2x before tag 3 recurs.
  hipMemsetAsync(h_pair, 0xFF, HP_DW * 4, stream);

  build_frags<<<dim3(512), dim3(256), 0, stream>>>(Wx, fragWx);
  build_frags<<<dim3(512), dim3(256), 0, stream>>>(Wh, fragWh);

  void* args[] = {(void*)&x,      (void*)&len,    (void*)&bias, (void*)&fragWx,
                  (void*)&fragWh, (void*)&h_pair, (void*)&out};
  hipLaunchCooperativeKernel((void*)lstm7, dim3(NWG), dim3(NTHR), args, 0, stream);
}